// Round 2
// baseline (1141.132 us; speedup 1.0000x reference)
//
#include <hip/hip_runtime.h>
#include <hip/hip_bf16.h>

#define NN 8192
#define RW 10
#define H1 100
#define H2 100
#define NB 256

constexpr int CHUNK = 256;            // m-values per chunk (64 lanes x 4)
constexpr int NCHUNKS = NN / CHUNK;   // 32

// Kernel A: hopX[k][n][d] = sum_m hop_k[n][m] * X[m][d]
// One row per wave, 4 waves/block. NO LDS, NO barriers: each lane loads its
// own 40 X floats (10x float4, coalesced, L2-resident) + 3 hop float4 per
// chunk, 120 unrolled FMAs. Loads from successive chunks overlap freely.
__global__ __launch_bounds__(256) void hopx_kernel(
    const float* __restrict__ X,
    const float* __restrict__ hop1,
    const float* __restrict__ hop2,
    const float* __restrict__ hop3,
    float* __restrict__ hopX)
{
    const int tid  = threadIdx.x;
    const int wave = tid >> 6;
    const int lane = tid & 63;
    const int n    = blockIdx.x * 4 + wave;

    float acc[3][RW];
    #pragma unroll
    for (int k = 0; k < 3; ++k)
        #pragma unroll
        for (int d = 0; d < RW; ++d) acc[k][d] = 0.f;

    const float* __restrict__ r1 = hop1 + (size_t)n * NN;
    const float* __restrict__ r2 = hop2 + (size_t)n * NN;
    const float* __restrict__ r3 = hop3 + (size_t)n * NN;

    for (int c = 0; c < NCHUNKS; ++c) {
        const int mi = c * CHUNK + 4 * lane;   // this lane's 4 m-values

        // X[mi..mi+3][0..9] = 40 consecutive floats at X + mi*10 (160B-aligned)
        float4 xq[10];
        const float4* xp = (const float4*)(X + (size_t)mi * RW);
        #pragma unroll
        for (int q = 0; q < 10; ++q) xq[q] = xp[q];
        const float* xf = (const float*)&xq[0];

        float4 h0 = *(const float4*)(r1 + mi);
        float4 h1 = *(const float4*)(r2 + mi);
        float4 h2 = *(const float4*)(r3 + mi);
        const float hv0[4] = {h0.x, h0.y, h0.z, h0.w};
        const float hv1[4] = {h1.x, h1.y, h1.z, h1.w};
        const float hv2[4] = {h2.x, h2.y, h2.z, h2.w};

        #pragma unroll
        for (int j = 0; j < 4; ++j) {
            #pragma unroll
            for (int d = 0; d < RW; ++d) {
                const float xv = xf[j * RW + d];
                acc[0][d] += hv0[j] * xv;
                acc[1][d] += hv1[j] * xv;
                acc[2][d] += hv2[j] * xv;
            }
        }
    }

    // wave-wide reduction (64 lanes), lane 0 writes 30 results for this row
    #pragma unroll
    for (int k = 0; k < 3; ++k) {
        #pragma unroll
        for (int d = 0; d < RW; ++d) {
            float v = acc[k][d];
            #pragma unroll
            for (int off = 32; off > 0; off >>= 1)
                v += __shfl_down(v, off, 64);
            if (lane == 0)
                hopX[((size_t)k * NN + n) * RW + d] = v;
        }
    }
}

// Kernel B: one block per batch segment b.
// h[k][n] = relu(inp[k][n] @ W1[k] + b1[k]) accumulated (segment-sum) in
// registers across the segment's nodes (thread t<400 owns (k,h)=(t/100,t%100)),
// then pooled[b] = sum_k Hacc[k] @ W2[k] + count_b * sum_k b2[k]. No atomics.
__global__ __launch_bounds__(512) void mlp_pool_kernel(
    const float* __restrict__ X,
    const float* __restrict__ hopX,
    const int*   __restrict__ batch_idx,
    const float* __restrict__ W1,
    const float* __restrict__ b1,
    const float* __restrict__ W2,
    const float* __restrict__ b2,
    float* __restrict__ out)
{
    const int b = blockIdx.x;
    const int t = threadIdx.x;

    // binary-search segment [lo, hi) in sorted batch_idx (uniform per block)
    int lo, hi;
    {
        int l = 0, r = NN;
        while (l < r) { int mid = (l + r) >> 1; if (batch_idx[mid] < b) l = mid + 1; else r = mid; }
        lo = l;
        r = NN;
        while (l < r) { int mid = (l + r) >> 1; if (batch_idx[mid] < b + 1) l = mid + 1; else r = mid; }
        hi = l;
    }

    __shared__ float inpS[8][40];   // 8 nodes x (4k x 10d)
    __shared__ float hbuf[400];

    const int k = t / 100;
    const int h = t % 100;
    float w1col[RW];
    float bias = 0.f;
    if (t < 400) {
        #pragma unroll
        for (int d = 0; d < RW; ++d)
            w1col[d] = W1[k * (RW * H1) + d * H1 + h];
        bias = b1[k * H1 + h];
    }

    float hacc = 0.f;
    for (int base = lo; base < hi; base += 8) {
        const int cnt = min(8, hi - base);
        // stage inp for up to 8 nodes: slot = kk*10+dd; kk==0 -> X else hopX
        if (t < cnt * 40) {
            const int nn   = base + t / 40;
            const int slot = t % 40;
            const int kk   = slot / 10, dd = slot % 10;
            inpS[t / 40][slot] = (kk == 0)
                ? X[(size_t)nn * RW + dd]
                : hopX[((size_t)(kk - 1) * NN + nn) * RW + dd];
        }
        __syncthreads();
        if (t < 400) {
            for (int j = 0; j < cnt; ++j) {
                float v = bias;
                #pragma unroll
                for (int d = 0; d < RW; ++d)
                    v += inpS[j][k * RW + d] * w1col[d];
                hacc += fmaxf(v, 0.f);
            }
        }
        __syncthreads();
    }

    if (t < 400) hbuf[t] = hacc;
    __syncthreads();

    if (t < H2) {
        float acc2 = 0.f;
        #pragma unroll 8
        for (int kh = 0; kh < 4 * H1; ++kh)
            acc2 += hbuf[kh] * W2[kh * H2 + t];   // hbuf broadcast, W2 coalesced
        const float bs = b2[t] + b2[H2 + t] + b2[2 * H2 + t] + b2[3 * H2 + t];
        out[b * H2 + t] = acc2 + (float)(hi - lo) * bs;
    }
}

extern "C" void kernel_launch(void* const* d_in, const int* in_sizes, int n_in,
                              void* d_out, int out_size, void* d_ws, size_t ws_size,
                              hipStream_t stream) {
    const float* walk_feats = (const float*)d_in[0];
    const float* hop1       = (const float*)d_in[1];
    const float* hop2       = (const float*)d_in[2];
    const float* hop3       = (const float*)d_in[3];
    const int*   batch_idx  = (const int*)  d_in[4];
    const float* W1         = (const float*)d_in[5];
    const float* b1         = (const float*)d_in[6];
    const float* W2         = (const float*)d_in[7];
    const float* b2         = (const float*)d_in[8];
    float* out = (float*)d_out;

    float* hopX = (float*)d_ws;   // 3 * 8192 * 10 floats = 983 KB

    hopx_kernel<<<NN / 4, 256, 0, stream>>>(walk_feats, hop1, hop2, hop3, hopX);
    mlp_pool_kernel<<<NB, 512, 0, stream>>>(walk_feats, hopX, batch_idx,
                                            W1, b1, W2, b2, out);
}